// Round 1
// baseline (310.728 us; speedup 1.0000x reference)
//
#include <hip/hip_runtime.h>

#define F 64
#define H 64
#define L 2
#define M_ROWS 128
#define HPAD 72          // bf16 elems per LDS row: 144 B (16B-aligned, <=2-way bank alias on reads)
#define NT 256

typedef __bf16 bf16;
typedef __attribute__((ext_vector_type(8))) __bf16 bf16x8;
typedef __attribute__((ext_vector_type(2))) __bf16 bf16x2;
typedef __attribute__((ext_vector_type(4))) float f32x4;

__device__ __forceinline__ float celu1(float v) {
    // CELU(alpha=1): x>0 ? x : exp(x)-1
    float e = __expf(v) - 1.0f;
    return v > 0.0f ? v : e;
}

__global__ __launch_bounds__(NT) void mlp64(
    const float* __restrict__ x,
    const float* __restrict__ w_in,
    const float* __restrict__ b_in,
    const float* __restrict__ w_hid,
    const float* __restrict__ b_hid,
    const float* __restrict__ w_out,
    const float* __restrict__ b_out,
    float* __restrict__ out)
{
    const int f    = blockIdx.x & (F - 1);
    const int tile = blockIdx.x >> 6;
    const int row0 = tile * M_ROWS;
    const int t    = threadIdx.x;

    __shared__ __align__(16) bf16 hbuf[M_ROWS][HPAD];
    __shared__ float xs[M_ROWS];
    __shared__ float s_win[H], s_bin[H], s_wout[H], s_bh[L][H];
    __shared__ float s_bout;

    // ---- stage small per-feature tensors ----
    if (t < M_ROWS) xs[t] = x[(size_t)(row0 + t) * F + f];
    if (t < H) {
        s_win[t] = w_in[f * H + t];
        s_bin[t] = b_in[f * H + t];
    } else if (t < 2 * H) {
        s_wout[t - H] = w_out[f * H + (t - H)];
    } else {
        int j = t - 2 * H;                       // 0..127 -> [l][c]
        s_bh[j >> 6][j & (H - 1)] = b_hid[((size_t)(j >> 6) * F + f) * H + (j & (H - 1))];
    }
    if (t == 0) s_bout = b_out[f];
    __syncthreads();

    // ---- first layer: h = celu(x * w_in + b_in), wave-private rows (t>>1 keeps wave ownership) ----
    {
        const int row = t >> 1;
        const int c0  = (t & 1) * 32;
        const float xv = xs[row];
        #pragma unroll
        for (int c = 0; c < 32; c += 2) {
            float v0 = celu1(fmaf(xv, s_win[c0 + c],     s_bin[c0 + c]));
            float v1 = celu1(fmaf(xv, s_win[c0 + c + 1], s_bin[c0 + c + 1]));
            bf16x2 p; p.x = (bf16)v0; p.y = (bf16)v1;
            *(bf16x2*)&hbuf[row][c0 + c] = p;
        }
    }
    // From here on, each wave reads/writes only its own 32 rows -> no inter-layer barrier.

    const int lane = t & 63;
    const int wave = t >> 6;
    const int l15  = lane & 15;
    const int quad = lane >> 4;
    const int wrow = wave * 32;

    #pragma unroll
    for (int l = 0; l < L; ++l) {
        const float* Wl = w_hid + (size_t)(l * F + f) * H * H;  // [out=64][in=64]

        // B fragments: B[k][n] = W[n][k]; lane holds W[n=n16+l15][k0..k0+7], fp32->bf16
        bf16x8 Bf[4][2];
        #pragma unroll
        for (int n = 0; n < 4; ++n) {
            #pragma unroll
            for (int k = 0; k < 2; ++k) {
                const float* p = Wl + (size_t)(n * 16 + l15) * H + k * 32 + quad * 8;
                float4 aa = *(const float4*)p;
                float4 bb = *(const float4*)(p + 4);
                bf16x8 v;
                v[0] = (bf16)aa.x; v[1] = (bf16)aa.y; v[2] = (bf16)aa.z; v[3] = (bf16)aa.w;
                v[4] = (bf16)bb.x; v[5] = (bf16)bb.y; v[6] = (bf16)bb.z; v[7] = (bf16)bb.w;
                Bf[n][k] = v;
            }
        }

        // A fragments: A[m=l15][k=quad*8+j] as ds_read_b128
        bf16x8 Af[2][2];
        #pragma unroll
        for (int m = 0; m < 2; ++m)
            #pragma unroll
            for (int k = 0; k < 2; ++k)
                Af[m][k] = *(const bf16x8*)&hbuf[wrow + m * 16 + l15][k * 32 + quad * 8];

        // acc init with bias (bias depends on output col only -> broadcast into all 4 regs)
        f32x4 acc[2][4];
        #pragma unroll
        for (int n = 0; n < 4; ++n) {
            float bv = s_bh[l][n * 16 + l15];
            f32x4 cc = {bv, bv, bv, bv};
            #pragma unroll
            for (int m = 0; m < 2; ++m) acc[m][n] = cc;
        }

        #pragma unroll
        for (int n = 0; n < 4; ++n)
            #pragma unroll
            for (int m = 0; m < 2; ++m)
                #pragma unroll
                for (int k = 0; k < 2; ++k)
                    acc[m][n] = __builtin_amdgcn_mfma_f32_16x16x32_bf16(
                        Af[m][k], Bf[n][k], acc[m][n], 0, 0, 0);

        // epilogue: CELU + bf16 writeback (D: col=l15, row=quad*4+reg)
        #pragma unroll
        for (int m = 0; m < 2; ++m)
            #pragma unroll
            for (int r = 0; r < 4; ++r) {
                int rr = wrow + m * 16 + quad * 4 + r;
                #pragma unroll
                for (int n = 0; n < 4; ++n) {
                    float v = celu1(acc[m][n][r]);
                    hbuf[rr][n * 16 + l15] = (bf16)v;
                }
            }
    }

    __syncthreads();  // final layer reads rows across waves

    // ---- output layer: out[b,f] = dot(h, w_out[f]) + b_out[f], fp32 accumulate ----
    if (t < M_ROWS) {
        float sum = s_bout;
        #pragma unroll
        for (int j = 0; j < H; j += 2) {
            bf16x2 hv = *(const bf16x2*)&hbuf[t][j];
            sum = fmaf((float)hv.x, s_wout[j],     sum);
            sum = fmaf((float)hv.y, s_wout[j + 1], sum);
        }
        out[(size_t)(row0 + t) * F + f] = sum;
    }
}

extern "C" void kernel_launch(void* const* d_in, const int* in_sizes, int n_in,
                              void* d_out, int out_size, void* d_ws, size_t ws_size,
                              hipStream_t stream) {
    const float* x     = (const float*)d_in[0];
    const float* w_in  = (const float*)d_in[1];
    const float* b_in  = (const float*)d_in[2];
    const float* w_hid = (const float*)d_in[3];
    const float* b_hid = (const float*)d_in[4];
    const float* w_out = (const float*)d_in[5];
    const float* b_out = (const float*)d_in[6];
    float* out = (float*)d_out;

    const int Btot = in_sizes[0] / F;           // 32768
    dim3 grid((unsigned)((Btot / M_ROWS) * F)); // 256 tiles * 64 features = 16384 blocks
    dim3 block(NT);
    mlp64<<<grid, block, 0, stream>>>(x, w_in, b_in, w_hid, b_hid, w_out, b_out, out);
}

// Round 2
// 296.559 us; speedup vs baseline: 1.0478x; 1.0478x over previous
//
#include <hip/hip_runtime.h>

#define F 64
#define H 64
#define L 2
#define M_ROWS 128
#define HPAD 72          // bf16 elems per LDS row: 144 B (16B-aligned)
#define NT 256

typedef __bf16 bf16;
typedef __attribute__((ext_vector_type(8))) __bf16 bf16x8;
typedef __attribute__((ext_vector_type(4))) __bf16 bf16x4;
typedef __attribute__((ext_vector_type(4))) float f32x4;

__device__ __forceinline__ float celu1(float v) {
    // CELU(alpha=1): x>0 ? x : exp(x)-1
    float e = __expf(v) - 1.0f;
    return v > 0.0f ? v : e;
}

// one-shot fp32 -> bf16 convert of w_hid into d_ws (re-run every launch: ws is re-poisoned)
__global__ __launch_bounds__(256) void conv_w(const float* __restrict__ w, bf16* __restrict__ wc) {
    int i = (blockIdx.x * 256 + threadIdx.x) * 4;
    float4 v = *(const float4*)(w + i);
    bf16x4 o; o[0] = (bf16)v.x; o[1] = (bf16)v.y; o[2] = (bf16)v.z; o[3] = (bf16)v.w;
    *(bf16x4*)(wc + i) = o;
}

template<bool WBF16>
__global__ __launch_bounds__(NT) void mlp64(
    const float* __restrict__ x,
    const float* __restrict__ w_in,
    const float* __restrict__ b_in,
    const float* __restrict__ w_hid,
    const float* __restrict__ b_hid,
    const float* __restrict__ w_out,
    const float* __restrict__ b_out,
    const bf16*  __restrict__ wc,
    float* __restrict__ out)
{
    const int f    = blockIdx.x & (F - 1);
    const int tile = blockIdx.x >> 6;
    const int row0 = tile * M_ROWS;
    const int t    = threadIdx.x;
    const int lane = t & 63;
    const int wave = t >> 6;
    const int l15  = lane & 15;
    const int quad = lane >> 4;
    const int wrow = wave * 32;

    // each wave touches ONLY its own 32 rows of hbuf -> zero barriers in this kernel
    __shared__ __align__(16) bf16 hbuf[M_ROWS][HPAD];

    // ---- first layer: h = celu(x * w_in + b_in); 2 lanes per row, 32 cols each ----
    {
        const int row = lane >> 1;            // 0..31 within this wave
        const int c0  = (lane & 1) * 32;
        const float xv = x[(size_t)(row0 + wrow + row) * F + f];
        const float* wi = w_in + f * H + c0;  // L1-broadcast across waves
        const float* bi = b_in + f * H + c0;
        #pragma unroll
        for (int c = 0; c < 32; c += 4) {
            float4 wv = *(const float4*)(wi + c);
            float4 bv = *(const float4*)(bi + c);
            bf16x4 o;
            o[0] = (bf16)celu1(fmaf(xv, wv.x, bv.x));
            o[1] = (bf16)celu1(fmaf(xv, wv.y, bv.y));
            o[2] = (bf16)celu1(fmaf(xv, wv.z, bv.z));
            o[3] = (bf16)celu1(fmaf(xv, wv.w, bv.w));
            *(bf16x4*)&hbuf[wrow + row][c0 + c] = o;
        }
    }

    // ---- hidden layers: C^T[out][batch] = W[out][in] . h^T[in][batch] + b ----
    // A = W  : A[m=out=l15+16*m16][k=in=32*kk+quad*8+j]  -> contiguous [out][in] rows
    // B = h^T: B[k=in=32*kk+quad*8+j][n=batch=l15+16*n16] -> contiguous hbuf row reads
    // D      : col=batch=l15, row=out=16*m16+quad*4+reg  -> 4 contiguous outs per reg group
    #pragma unroll
    for (int l = 0; l < L; ++l) {
        bf16x8 Bh[2][2];
        #pragma unroll
        for (int n16 = 0; n16 < 2; ++n16)
            #pragma unroll
            for (int kk = 0; kk < 2; ++kk)
                Bh[n16][kk] = *(const bf16x8*)&hbuf[wrow + n16 * 16 + l15][kk * 32 + quad * 8];

        const size_t wbase  = (size_t)(l * F + f) * H * H;
        const float* bias_p = b_hid + (size_t)(l * F + f) * H;

        f32x4 acc[4][2];
        #pragma unroll
        for (int m16 = 0; m16 < 4; ++m16) {
            f32x4 b4 = *(const f32x4*)(bias_p + m16 * 16 + quad * 4);   // bias indexed by out=row
            acc[m16][0] = b4;
            acc[m16][1] = b4;

            bf16x8 Aw[2];
            if (WBF16) {
                const bf16* p = wc + wbase + (size_t)(m16 * 16 + l15) * H + quad * 8;
                Aw[0] = *(const bf16x8*)(p);
                Aw[1] = *(const bf16x8*)(p + 32);
            } else {
                const float* p = w_hid + wbase + (size_t)(m16 * 16 + l15) * H + quad * 8;
                #pragma unroll
                for (int kk = 0; kk < 2; ++kk) {
                    float4 aa = *(const float4*)(p + kk * 32);
                    float4 bb = *(const float4*)(p + kk * 32 + 4);
                    bf16x8 v;
                    v[0] = (bf16)aa.x; v[1] = (bf16)aa.y; v[2] = (bf16)aa.z; v[3] = (bf16)aa.w;
                    v[4] = (bf16)bb.x; v[5] = (bf16)bb.y; v[6] = (bf16)bb.z; v[7] = (bf16)bb.w;
                    Aw[kk] = v;
                }
            }

            #pragma unroll
            for (int n16 = 0; n16 < 2; ++n16)
                #pragma unroll
                for (int kk = 0; kk < 2; ++kk)
                    acc[m16][n16] = __builtin_amdgcn_mfma_f32_16x16x32_bf16(
                        Aw[kk], Bh[n16][kk], acc[m16][n16], 0, 0, 0);
        }

        // epilogue: CELU + packed 8B LDS writes (4 contiguous out-cols per store)
        #pragma unroll
        for (int m16 = 0; m16 < 4; ++m16)
            #pragma unroll
            for (int n16 = 0; n16 < 2; ++n16) {
                bf16x4 o;
                #pragma unroll
                for (int r = 0; r < 4; ++r) o[r] = (bf16)celu1(acc[m16][n16][r]);
                *(bf16x4*)&hbuf[wrow + n16 * 16 + l15][m16 * 16 + quad * 4] = o;
            }
    }

    // ---- output layer: 2 lanes per row, 32-elem half-dots + shuffle combine ----
    {
        const int row  = lane >> 1;
        const int half = lane & 1;
        const float* wo = w_out + f * H + half * 32;
        float sum = 0.0f;
        #pragma unroll
        for (int j = 0; j < 32; j += 8) {
            bf16x8 hv = *(const bf16x8*)&hbuf[wrow + row][half * 32 + j];
            float4 wv0 = *(const float4*)(wo + j);
            float4 wv1 = *(const float4*)(wo + j + 4);
            sum = fmaf((float)hv[0], wv0.x, sum);
            sum = fmaf((float)hv[1], wv0.y, sum);
            sum = fmaf((float)hv[2], wv0.z, sum);
            sum = fmaf((float)hv[3], wv0.w, sum);
            sum = fmaf((float)hv[4], wv1.x, sum);
            sum = fmaf((float)hv[5], wv1.y, sum);
            sum = fmaf((float)hv[6], wv1.z, sum);
            sum = fmaf((float)hv[7], wv1.w, sum);
        }
        sum += __shfl_xor(sum, 1, 64);
        if (!half) out[(size_t)(row0 + wrow + row) * F + f] = sum + b_out[f];
    }
}

extern "C" void kernel_launch(void* const* d_in, const int* in_sizes, int n_in,
                              void* d_out, int out_size, void* d_ws, size_t ws_size,
                              hipStream_t stream) {
    const float* x     = (const float*)d_in[0];
    const float* w_in  = (const float*)d_in[1];
    const float* b_in  = (const float*)d_in[2];
    const float* w_hid = (const float*)d_in[3];
    const float* b_hid = (const float*)d_in[4];
    const float* w_out = (const float*)d_in[5];
    const float* b_out = (const float*)d_in[6];
    float* out = (float*)d_out;

    const int Btot = in_sizes[0] / F;            // 32768
    dim3 grid((unsigned)((Btot / M_ROWS) * F));  // 256 tiles * 64 features
    dim3 block(NT);

    const int wn = L * F * H * H;                // 524288 elems
    if (ws_size >= (size_t)wn * sizeof(bf16)) {
        bf16* wc = (bf16*)d_ws;
        conv_w<<<wn / (256 * 4), 256, 0, stream>>>(w_hid, wc);
        mlp64<true><<<grid, block, 0, stream>>>(x, w_in, b_in, w_hid, b_hid, w_out, b_out, wc, out);
    } else {
        mlp64<false><<<grid, block, 0, stream>>>(x, w_in, b_in, w_hid, b_hid, w_out, b_out, nullptr, out);
    }
}

// Round 3
// 272.183 us; speedup vs baseline: 1.1416x; 1.0896x over previous
//
#include <hip/hip_runtime.h>

#define F 64
#define H 64
#define HPAD 72          // bf16 elems per LDS row: 144 B (16B-aligned; Bh reads & epilogue writes bank-even)
#define NT 256
#define TILE_ROWS 128
#define ITERS 8
#define ROWS_PER_BLOCK (TILE_ROWS * ITERS)   // 1024

typedef __bf16 bf16;
typedef __attribute__((ext_vector_type(8))) __bf16 bf16x8;
typedef __attribute__((ext_vector_type(4))) __bf16 bf16x4;
typedef __attribute__((ext_vector_type(4))) float f32x4;

__device__ __forceinline__ float celu1(float v) {
    // CELU(alpha=1): x>0 ? x : exp(x)-1
    float e = __expf(v) - 1.0f;
    return v > 0.0f ? v : e;
}

// one-shot fp32 -> bf16 convert of w_hid into d_ws (re-run every launch: ws is re-poisoned)
__global__ __launch_bounds__(256) void conv_w(const float* __restrict__ w, bf16* __restrict__ wc) {
    int i = (blockIdx.x * 256 + threadIdx.x) * 4;
    float4 v = *(const float4*)(w + i);
    bf16x4 o; o[0] = (bf16)v.x; o[1] = (bf16)v.y; o[2] = (bf16)v.z; o[3] = (bf16)v.w;
    *(bf16x4*)(wc + i) = o;
}

// Block = one feature f x 1024 rows. 4 waves, each owns 32 rows per 128-row tile, 8 tiles.
// All three layers are MFMA on the transposed product C^T[out][batch]:
//   A[m=out][k=in] (W rows, register-resident), B[k=in][n=batch] (hbuf rows / x regs),
//   D: col=batch=lane&15, row=out=16*m16+quad*4+reg.
// Layer 1 (in=1) is a compensated rank-1: k0=w_hi*x_hi, k1=w_lo*x_hi, k2=w_hi*x_lo.
// Layer 2 output is dotted with w_out in registers (quad shfl reduce) -> no LDS round trip.
template<bool WBF16>
__global__ __launch_bounds__(NT, 3) void mlp64(
    const float* __restrict__ x,
    const float* __restrict__ w_in,
    const float* __restrict__ b_in,
    const float* __restrict__ w_hid,
    const float* __restrict__ b_hid,
    const float* __restrict__ w_out,
    const float* __restrict__ b_out,
    const bf16*  __restrict__ wc,
    float* __restrict__ out)
{
    const int f    = blockIdx.x & (F - 1);
    const int blk  = blockIdx.x >> 6;
    const int row0 = blk * ROWS_PER_BLOCK;
    const int t    = threadIdx.x;
    const int lane = t & 63;
    const int wave = t >> 6;
    const int l15  = lane & 15;
    const int quad = lane >> 4;
    const int wrow = wave * 32;

    __shared__ __align__(16) bf16 hbuf[TILE_ROWS][HPAD];  // wave-private 32-row slices
    __shared__ float s_bias[3][H];                        // [0]=b_in, [1]=b_hid l0, [2]=b_hid l1

    // ---- stage biases (one barrier for the whole kernel) ----
    if (t < H)           s_bias[0][t]       = b_in[f * H + t];
    else if (t < 2 * H)  s_bias[1][t - H]   = b_hid[(0 * F + f) * H + (t - H)];
    else if (t < 3 * H)  s_bias[2][t - 2*H] = b_hid[(1 * F + f) * H + (t - 2*H)];
    __syncthreads();

    // ---- hoist weights into registers (amortized over 8 tiles) ----
    bf16x8 Aw[2][4][2];          // [layer][m16][kk] : A[m=16*m16+l15][k=32*kk+quad*8+j]
    #pragma unroll
    for (int l = 0; l < 2; ++l)
        #pragma unroll
        for (int m = 0; m < 4; ++m) {
            if (WBF16) {
                const bf16* p = wc + ((size_t)(l * F + f) * H + m * 16 + l15) * H + quad * 8;
                Aw[l][m][0] = *(const bf16x8*)p;
                Aw[l][m][1] = *(const bf16x8*)(p + 32);
            } else {
                const float* p = w_hid + ((size_t)(l * F + f) * H + m * 16 + l15) * H + quad * 8;
                #pragma unroll
                for (int kk = 0; kk < 2; ++kk) {
                    float4 aa = *(const float4*)(p + kk * 32);
                    float4 bb = *(const float4*)(p + kk * 32 + 4);
                    bf16x8 v;
                    v[0] = (bf16)aa.x; v[1] = (bf16)aa.y; v[2] = (bf16)aa.z; v[3] = (bf16)aa.w;
                    v[4] = (bf16)bb.x; v[5] = (bf16)bb.y; v[6] = (bf16)bb.z; v[7] = (bf16)bb.w;
                    Aw[l][m][kk] = v;
                }
            }
        }

    bf16x8 A1[4];                // layer-1 A frags: quad 0 holds (w_hi, w_lo, w_hi, 0...)
    #pragma unroll
    for (int m = 0; m < 4; ++m) {
        float w  = w_in[f * H + m * 16 + l15];
        bf16 hi  = (bf16)w;
        bf16 lo  = (bf16)(w - (float)hi);
        bf16x8 v = {};
        if (quad == 0) { v[0] = hi; v[1] = lo; v[2] = hi; }
        A1[m] = v;
    }

    f32x4 wo4[4];                // w_out[16*m16+quad*4+r]
    #pragma unroll
    for (int m = 0; m < 4; ++m)
        wo4[m] = *(const f32x4*)(w_out + f * H + m * 16 + quad * 4);
    const float bo = b_out[f];

    // ---- main loop over 8 row tiles ----
    float xc0 = x[(size_t)(row0 + wrow + l15) * F + f];
    float xc1 = x[(size_t)(row0 + wrow + 16 + l15) * F + f];

    for (int it = 0; it < ITERS; ++it) {
        const int rbase = row0 + it * TILE_ROWS + wrow;

        // B1 frags: quad 0 holds (x_hi, x_hi, x_lo, 0...)
        bf16x8 B1[2];
        {
            bf16 h0 = (bf16)xc0, h1 = (bf16)xc1;
            bf16 l0 = (bf16)(xc0 - (float)h0), l1 = (bf16)(xc1 - (float)h1);
            bf16x8 v0 = {}, v1 = {};
            if (quad == 0) { v0[0] = h0; v0[1] = h0; v0[2] = l0;
                             v1[0] = h1; v1[1] = h1; v1[2] = l1; }
            B1[0] = v0; B1[1] = v1;
        }
        // prefetch next tile's x (wave-uniform branch)
        float xn0 = 0.0f, xn1 = 0.0f;
        if (it + 1 < ITERS) {
            xn0 = x[(size_t)(rbase + TILE_ROWS + l15) * F + f];
            xn1 = x[(size_t)(rbase + TILE_ROWS + 16 + l15) * F + f];
        }

        f32x4 acc[4][2];

        // ---- layer 1: one MFMA per (m,n); bias rides in as C operand ----
        #pragma unroll
        for (int m = 0; m < 4; ++m) {
            f32x4 c0 = *(const f32x4*)&s_bias[0][m * 16 + quad * 4];
            #pragma unroll
            for (int n = 0; n < 2; ++n)
                acc[m][n] = __builtin_amdgcn_mfma_f32_16x16x32_bf16(A1[m], B1[n], c0, 0, 0, 0);
        }
        #pragma unroll
        for (int m = 0; m < 4; ++m)
            #pragma unroll
            for (int n = 0; n < 2; ++n) {
                bf16x4 o;
                #pragma unroll
                for (int r = 0; r < 4; ++r) o[r] = (bf16)celu1(acc[m][n][r]);
                *(bf16x4*)&hbuf[wrow + n * 16 + l15][m * 16 + quad * 4] = o;
            }

        // ---- hidden layer 1 (hbuf -> hbuf) ----
        {
            bf16x8 Bh[2][2];
            #pragma unroll
            for (int n = 0; n < 2; ++n)
                #pragma unroll
                for (int kk = 0; kk < 2; ++kk)
                    Bh[n][kk] = *(const bf16x8*)&hbuf[wrow + n * 16 + l15][kk * 32 + quad * 8];
            #pragma unroll
            for (int m = 0; m < 4; ++m) {
                f32x4 c0 = *(const f32x4*)&s_bias[1][m * 16 + quad * 4];
                #pragma unroll
                for (int n = 0; n < 2; ++n) {
                    f32x4 a = __builtin_amdgcn_mfma_f32_16x16x32_bf16(Aw[0][m][0], Bh[n][0], c0, 0, 0, 0);
                    acc[m][n] = __builtin_amdgcn_mfma_f32_16x16x32_bf16(Aw[0][m][1], Bh[n][1], a, 0, 0, 0);
                }
            }
            #pragma unroll
            for (int m = 0; m < 4; ++m)
                #pragma unroll
                for (int n = 0; n < 2; ++n) {
                    bf16x4 o;
                    #pragma unroll
                    for (int r = 0; r < 4; ++r) o[r] = (bf16)celu1(acc[m][n][r]);
                    *(bf16x4*)&hbuf[wrow + n * 16 + l15][m * 16 + quad * 4] = o;
                }
        }

        // ---- hidden layer 2 + output dot (no LDS round trip) ----
        {
            bf16x8 Bh[2][2];
            #pragma unroll
            for (int n = 0; n < 2; ++n)
                #pragma unroll
                for (int kk = 0; kk < 2; ++kk)
                    Bh[n][kk] = *(const bf16x8*)&hbuf[wrow + n * 16 + l15][kk * 32 + quad * 8];
            #pragma unroll
            for (int m = 0; m < 4; ++m) {
                f32x4 c0 = *(const f32x4*)&s_bias[2][m * 16 + quad * 4];
                #pragma unroll
                for (int n = 0; n < 2; ++n) {
                    f32x4 a = __builtin_amdgcn_mfma_f32_16x16x32_bf16(Aw[1][m][0], Bh[n][0], c0, 0, 0, 0);
                    acc[m][n] = __builtin_amdgcn_mfma_f32_16x16x32_bf16(Aw[1][m][1], Bh[n][1], a, 0, 0, 0);
                }
            }
            #pragma unroll
            for (int n = 0; n < 2; ++n) {
                float s = 0.0f;
                #pragma unroll
                for (int m = 0; m < 4; ++m)
                    #pragma unroll
                    for (int r = 0; r < 4; ++r)
                        s = fmaf(celu1(acc[m][n][r]), wo4[m][r], s);
                s += __shfl_xor(s, 16, 64);   // reduce over quads (out-dim lives on quad*4+r, 16*m)
                s += __shfl_xor(s, 32, 64);
                if (quad == 0)
                    out[(size_t)(rbase + n * 16 + l15) * F + f] = s + bo;
            }
        }

        xc0 = xn0; xc1 = xn1;
    }
}

extern "C" void kernel_launch(void* const* d_in, const int* in_sizes, int n_in,
                              void* d_out, int out_size, void* d_ws, size_t ws_size,
                              hipStream_t stream) {
    const float* x     = (const float*)d_in[0];
    const float* w_in  = (const float*)d_in[1];
    const float* b_in  = (const float*)d_in[2];
    const float* w_hid = (const float*)d_in[3];
    const float* b_hid = (const float*)d_in[4];
    const float* w_out = (const float*)d_in[5];
    const float* b_out = (const float*)d_in[6];
    float* out = (float*)d_out;

    const int Btot = in_sizes[0] / F;                       // 32768
    dim3 grid((unsigned)((Btot / ROWS_PER_BLOCK) * F));     // 32 * 64 = 2048 blocks
    dim3 block(NT);

    const int wn = 2 * F * H * H;                           // 524288 elems
    if (ws_size >= (size_t)wn * sizeof(bf16)) {
        bf16* wcp = (bf16*)d_ws;
        conv_w<<<wn / (256 * 4), 256, 0, stream>>>(w_hid, wcp);
        mlp64<true><<<grid, block, 0, stream>>>(x, w_in, b_in, w_hid, b_hid, w_out, b_out, wcp, out);
    } else {
        mlp64<false><<<grid, block, 0, stream>>>(x, w_in, b_in, w_hid, b_hid, w_out, b_out, nullptr, out);
    }
}